// Round 3
// baseline (972.840 us; speedup 1.0000x reference)
//
#include <hip/hip_runtime.h>

typedef __attribute__((ext_vector_type(8))) short short8;
typedef __attribute__((ext_vector_type(4))) float f32x4;

static constexpr int NB = 16;     // batch
static constexpr int NT = 128;    // seq len
static constexpr int NS = 1024;   // states
static constexpr int NV = 32000;  // vocab

// ---------- helpers ----------
__device__ __forceinline__ unsigned short f2bf(float f) {
  unsigned int u = __float_as_uint(f);
  u = (u + 0x7fffu + ((u >> 16) & 1u)) >> 16;   // RNE, inputs are finite positive
  return (unsigned short)u;
}

__device__ __forceinline__ void lse_add(float& mx, float& s, float x) {
  float nm = fmaxf(mx, x);
  s = s * __expf(mx - nm) + __expf(x - nm);
  mx = nm;
}
__device__ __forceinline__ void lse_comb(float& mx, float& s, float m2, float s2) {
  float nm = fmaxf(mx, m2);
  s = s * __expf(mx - nm) + s2 * __expf(m2 - nm);
  mx = nm;
}

// ---------- phase A1: transition column LSE (log_softmax dim=0) + log_pi ----------
__global__ void __launch_bounds__(256)
prep_trans(const float* __restrict__ Tu, const float* __restrict__ prior,
           float* __restrict__ colLSE, float* __restrict__ log_pi) {
  __shared__ float smx[4][64];
  __shared__ float ssm[4][64];
  const int tid = threadIdx.x;
  const int wg = blockIdx.x;
  if (wg < 16) {
    const int col = wg * 64 + (tid & 63);
    const int seg = tid >> 6;
    float mx = -INFINITY, s = 0.f;
    const float* p = Tu + (size_t)(seg * 256) * NS + col;
    for (int m = 0; m < 256; ++m) lse_add(mx, s, p[(size_t)m * NS]);
    smx[seg][tid & 63] = mx;
    ssm[seg][tid & 63] = s;
    __syncthreads();
    if (tid < 64) {
      float M = smx[0][tid], S = ssm[0][tid];
      for (int k = 1; k < 4; ++k) lse_comb(M, S, smx[k][tid], ssm[k][tid]);
      colLSE[wg * 64 + tid] = M + __logf(S);
    }
  } else {
    // state priors: log_softmax over 1024
    float mx = -INFINITY, s = 0.f;
    for (int i = tid; i < NS; i += 256) lse_add(mx, s, prior[i]);
    for (int o = 1; o < 64; o <<= 1) {
      float m2 = __shfl_xor(mx, o), s2 = __shfl_xor(s, o);
      lse_comb(mx, s, m2, s2);
    }
    const int wv = tid >> 6, ln = tid & 63;
    if (ln == 0) { smx[0][wv] = mx; ssm[0][wv] = s; }
    __syncthreads();
    float M = smx[0][0], S = ssm[0][0];
    for (int k = 1; k < 4; ++k) lse_comb(M, S, smx[0][k], ssm[0][k]);
    const float lse = M + __logf(S);
    for (int i = tid; i < NS; i += 256) log_pi[i] = prior[i] - lse;
  }
}

// ---------- phase A2: T_prob[m][n] = exp(Tu[m][n] - colLSE[n]) as bf16 ----------
__global__ void __launch_bounds__(256)
prep_tprob(const float* __restrict__ Tu, const float* __restrict__ colLSE,
           unsigned short* __restrict__ Tp) {
  const int i = (blockIdx.x * 256 + threadIdx.x) * 4;
  const float4 tu = *(const float4*)(Tu + i);
  const float4 cl = *(const float4*)(colLSE + (i & (NS - 1)));
  ushort4 o;
  o.x = f2bf(__expf(tu.x - cl.x));
  o.y = f2bf(__expf(tu.y - cl.y));
  o.z = f2bf(__expf(tu.z - cl.z));
  o.w = f2bf(__expf(tu.w - cl.w));
  *(ushort4*)(Tp + i) = o;
}

// ---------- phase A3: emission row LSE (online) + token gather ----------
// emit_g[j][n] = emission[n][tok[j]] - rowLSE[n],  j = b*NT + t
__global__ void __launch_bounds__(256)
prep_emit(const float* __restrict__ Em, const int* __restrict__ tok,
          float* __restrict__ emit_g) {
  __shared__ float wm[4], wsv[4];
  const int n = blockIdx.x;
  const int tid = threadIdx.x;
  const float* row = Em + (size_t)n * NV;
  float mx = -INFINITY, s = 0.f;
  for (int i = tid; i < NV; i += 256) lse_add(mx, s, row[i]);   // 125 iters exactly
  for (int o = 1; o < 64; o <<= 1) {
    float m2 = __shfl_xor(mx, o), s2 = __shfl_xor(s, o);
    lse_comb(mx, s, m2, s2);
  }
  const int wv = tid >> 6, ln = tid & 63;
  if (ln == 0) { wm[wv] = mx; wsv[wv] = s; }
  __syncthreads();
  float M = wm[0], S = wsv[0];
  for (int k = 1; k < 4; ++k) lse_comb(M, S, wm[k], wsv[k]);
  const float lse = M + __logf(S);
  for (int j = tid; j < NB * NT; j += 256)
    emit_g[(size_t)j * NS + n] = row[tok[j]] - lse;             // row is L2/L3-hot
}

// ---------- group barrier: monotonic counter, device scope ----------
__device__ __forceinline__ void group_barrier(unsigned int* ctr, unsigned int target) {
  __syncthreads();                      // drains this wg's vmem (vmcnt(0) before s_barrier)
  if (threadIdx.x == 0) {
    __hip_atomic_fetch_add(ctr, 1u, __ATOMIC_RELEASE, __HIP_MEMORY_SCOPE_AGENT);
    while (__hip_atomic_load(ctr, __ATOMIC_RELAXED, __HIP_MEMORY_SCOPE_AGENT) < target) {}
    __builtin_amdgcn_fence(__ATOMIC_ACQUIRE, "agent");
  }
  __syncthreads();
}

// ---------- phase B: per-batch chains. grid = 256 blocks: b = bid&15, g = bid>>4 ----------
// Each wg owns 64 output states [g*64, g*64+64), T_prob slice resident in VGPRs as
// MFMA A-fragments. One device-scope group barrier (16 wgs) per timestep.
__global__ void __launch_bounds__(256)
hmm_chain(const unsigned short* __restrict__ Tp, const float* __restrict__ emit_g,
          const float* __restrict__ log_pi, const int* __restrict__ length,
          float* __restrict__ alpha, unsigned int* __restrict__ bar,
          float* __restrict__ out) {
  __shared__ __align__(16) unsigned short A_lds[NS];  // bf16 exp(alpha - amax)
  __shared__ float wred[8];
  const int tid = threadIdx.x;
  const int b = blockIdx.x & 15;
  const int g = blockIdx.x >> 4;
  const int wv = tid >> 6;
  const int lane = tid & 63;
  const int l15 = lane & 15;
  const int kg = lane >> 4;
  const int mwave = g * 64 + wv * 16;      // this wave's 16 output rows

  // T fragments: A-layout for mfma_f32_16x16x32_bf16: m = lane&15, k = (lane>>4)*8 + j
  short8 tf[32];
  {
    const unsigned short* tb = Tp + (size_t)(mwave + l15) * NS + kg * 8;
#pragma unroll
    for (int i = 0; i < 32; ++i) tf[i] = *(const short8*)(tb + i * 32);
  }

  int len = length[b];
  len = len < 1 ? 1 : (len > NT ? NT : len);
  unsigned int* ctr = bar + b * 16;        // 64B-padded per group
  unsigned int barcnt = 0;

  // alpha0 = emit(t=0) + log_pi
  if (tid < 64) {
    const int m = g * 64 + tid;
    alpha[(size_t)b * NS + m] = emit_g[(size_t)(b * NT) * NS + m] + log_pi[m];
  }
  group_barrier(ctr, 16u * (++barcnt));

  int p = 0;
  for (int t = 1; t < len; ++t) {
    // 1. read full alpha[p][b][:], block-reduce max
    const float* ap = alpha + ((size_t)p * NB + b) * NS;
    const float4 av = *(const float4*)(ap + tid * 4);
    float mx = fmaxf(fmaxf(av.x, av.y), fmaxf(av.z, av.w));
#pragma unroll
    for (int o = 1; o < 64; o <<= 1) mx = fmaxf(mx, __shfl_xor(mx, o));
    if (lane == 0) wred[wv] = mx;
    __syncthreads();
    const float amax = fmaxf(fmaxf(wred[0], wred[1]), fmaxf(wred[2], wred[3]));

    // 2. exp, pack bf16 into LDS
    ushort4 e4;
    e4.x = f2bf(__expf(av.x - amax));
    e4.y = f2bf(__expf(av.y - amax));
    e4.z = f2bf(__expf(av.z - amax));
    e4.w = f2bf(__expf(av.w - amax));
    *(ushort4*)(A_lds + tid * 4) = e4;
    __syncthreads();

    // 3. matvec via MFMA. B operand broadcast over all 16 columns -> every lane
    //    ends with S[m = mwave + (lane>>4)*4 + r] in acc[r] (C/D: row=(l>>4)*4+r).
    f32x4 a0 = {0.f, 0.f, 0.f, 0.f}, a1 = a0, a2 = a0, a3 = a0;
#pragma unroll
    for (int j = 0; j < 8; ++j) {
      a0 = __builtin_amdgcn_mfma_f32_16x16x32_bf16(tf[j],      *(const short8*)(A_lds + (j)      * 32 + kg * 8), a0, 0, 0, 0);
      a1 = __builtin_amdgcn_mfma_f32_16x16x32_bf16(tf[8 + j],  *(const short8*)(A_lds + (8 + j)  * 32 + kg * 8), a1, 0, 0, 0);
      a2 = __builtin_amdgcn_mfma_f32_16x16x32_bf16(tf[16 + j], *(const short8*)(A_lds + (16 + j) * 32 + kg * 8), a2, 0, 0, 0);
      a3 = __builtin_amdgcn_mfma_f32_16x16x32_bf16(tf[24 + j], *(const short8*)(A_lds + (24 + j) * 32 + kg * 8), a3, 0, 0, 0);
    }
    const f32x4 Sv = a0 + a1 + a2 + a3;

    // 4. alpha_new = emit + amax + ln(S); one lane per 4 rows writes float4
    const int pn = p ^ 1;
    if (l15 == 0) {
      const int m = mwave + kg * 4;
      const int j = b * NT + t;
      const float4 em = *(const float4*)(emit_g + (size_t)j * NS + m);
      float4 r;
      r.x = em.x + amax + 0.6931471805599453f * __log2f(Sv[0]);
      r.y = em.y + amax + 0.6931471805599453f * __log2f(Sv[1]);
      r.z = em.z + amax + 0.6931471805599453f * __log2f(Sv[2]);
      r.w = em.w + amax + 0.6931471805599453f * __log2f(Sv[3]);
      *(float4*)(alpha + ((size_t)pn * NB + b) * NS + m) = r;
    }
    group_barrier(ctr, 16u * (++barcnt));
    p = pn;
  }

  // leader wg computes out[b] = logsumexp(alpha at final t)
  if (g == 0) {
    const float* ap = alpha + ((size_t)p * NB + b) * NS;
    const float4 av = *(const float4*)(ap + tid * 4);
    float mx = fmaxf(fmaxf(av.x, av.y), fmaxf(av.z, av.w));
#pragma unroll
    for (int o = 1; o < 64; o <<= 1) mx = fmaxf(mx, __shfl_xor(mx, o));
    if (lane == 0) wred[wv] = mx;
    __syncthreads();
    const float amax = fmaxf(fmaxf(wred[0], wred[1]), fmaxf(wred[2], wred[3]));
    float s = __expf(av.x - amax) + __expf(av.y - amax) +
              __expf(av.z - amax) + __expf(av.w - amax);
#pragma unroll
    for (int o = 1; o < 64; o <<= 1) s += __shfl_xor(s, o);
    if (lane == 0) wred[4 + wv] = s;
    __syncthreads();
    if (tid == 0) out[b] = amax + __logf(wred[4] + wred[5] + wred[6] + wred[7]);
  }
}

// ---------- launch ----------
extern "C" void kernel_launch(void* const* d_in, const int* in_sizes, int n_in,
                              void* d_out, int out_size, void* d_ws, size_t ws_size,
                              hipStream_t stream) {
  const float* Em = (const float*)d_in[0];   // emission (N,V)
  const float* Tu = (const float*)d_in[1];   // transition (N,N)
  const float* Pr = (const float*)d_in[2];   // priors (N,)
  const int*   tok = (const int*)d_in[3];    // (B,T)
  const int*   len = (const int*)d_in[4];    // (B,)
  float* out = (float*)d_out;
  char* ws = (char*)d_ws;

  // ws layout (12 MB total)
  float* colLSE        = (float*)(ws + 0);            // 4 KB
  float* log_pi        = (float*)(ws + 4096);         // 4 KB
  unsigned int* bar    = (unsigned int*)(ws + 8192);  // 1 KB (16 groups * 64B)
  float* alpha         = (float*)(ws + 16384);        // 2*16*1024*4 = 128 KB
  unsigned short* Tp   = (unsigned short*)(ws + (256 << 10));  // 2 MB bf16
  float* emit_g        = (float*)(ws + (4u << 20));   // 8 MB

  hipMemsetAsync(bar, 0, 1024, stream);   // ws is poisoned 0xAA before every call
  prep_trans<<<17, 256, 0, stream>>>(Tu, Pr, colLSE, log_pi);
  prep_tprob<<<(NS * NS) / (256 * 4), 256, 0, stream>>>(Tu, colLSE, Tp);
  prep_emit<<<NS, 256, 0, stream>>>(Em, tok, emit_g);

  void* args[] = {(void*)&Tp, (void*)&emit_g, (void*)&log_pi, (void*)&len,
                  (void*)&alpha, (void*)&bar, (void*)&out};
  hipError_t e = hipLaunchCooperativeKernel((void*)hmm_chain, dim3(NB * 16), dim3(256),
                                            args, 0, stream);
  if (e != hipSuccess) {
    // fallback: 256 blocks at 1-2 per CU are co-resident on a 256-CU device
    hmm_chain<<<dim3(NB * 16), dim3(256), 0, stream>>>(Tp, emit_g, log_pi, len,
                                                       alpha, bar, out);
  }
}